// Round 1
// baseline (848.244 us; speedup 1.0000x reference)
//
#include <hip/hip_runtime.h>

#define EPS 1e-4f

constexpr int Bn = 64;
constexpr int Nn = 1024;
constexpr int Mn = 1024;
constexpr int NSPLIT = 8;            // row chunks per sample for col pass
constexpr int CHUNK = Nn / NSPLIT;   // 128 rows per chunk
constexpr int RPB = 8;               // rows per block in row pass

// r[b*N+n] = 1.0 everywhere (pass 0's column sum is UNMASKED over all rows,
// matching the reference which sums s+eps before any masking).
__global__ void init_r_kernel(float* __restrict__ r) {
    r[blockIdx.x * blockDim.x + threadIdx.x] = 1.0f;
}

// p[b][split][m] = sum over rows in chunk of (s+eps)*r[n]
// block = 256 threads, thread t covers cols 4t..4t+3 (float4, fully coalesced
// 4KB row segments); grid = (B, NSPLIT).
__global__ __launch_bounds__(256) void col_partial_kernel(
        const float* __restrict__ s, const float* __restrict__ r,
        float* __restrict__ p) {
    const int b = blockIdx.x;
    const int sp = blockIdx.y;
    const int m0 = threadIdx.x << 2;
    const float* srow = s + ((size_t)b * Nn + (size_t)sp * CHUNK) * Mn + m0;
    const float* rrow = r + b * Nn + sp * CHUNK;
    float ax = 0.f, ay = 0.f, az = 0.f, aw = 0.f;
    #pragma unroll 4
    for (int n = 0; n < CHUNK; ++n) {
        float4 v = *reinterpret_cast<const float4*>(srow + (size_t)n * Mn);
        float rn = rrow[n];   // wave-uniform -> scalar load
        ax += (v.x + EPS) * rn;
        ay += (v.y + EPS) * rn;
        az += (v.z + EPS) * rn;
        aw += (v.w + EPS) * rn;
    }
    float4 o = {ax, ay, az, aw};
    *reinterpret_cast<float4*>(p + ((size_t)(b * NSPLIT + sp)) * Mn + m0) = o;
}

// c[b][m] = (m < ncols[b] && colsum > 0) ? 1/colsum : 0
__global__ __launch_bounds__(256) void col_final_kernel(
        const float* __restrict__ p, const int* __restrict__ ncols,
        float* __restrict__ c) {
    const int b = blockIdx.x;
    const int m0 = threadIdx.x << 2;
    float sx = 0.f, sy = 0.f, sz = 0.f, sw = 0.f;
    #pragma unroll
    for (int k = 0; k < NSPLIT; ++k) {
        float4 v = *reinterpret_cast<const float4*>(
            p + ((size_t)(b * NSPLIT + k)) * Mn + m0);
        sx += v.x; sy += v.y; sz += v.z; sw += v.w;
    }
    const int nc = ncols[b];
    float4 o;
    o.x = (m0 + 0 < nc && sx > 0.f) ? 1.f / sx : 0.f;
    o.y = (m0 + 1 < nc && sy > 0.f) ? 1.f / sy : 0.f;
    o.z = (m0 + 2 < nc && sz > 0.f) ? 1.f / sz : 0.f;
    o.w = (m0 + 3 < nc && sw > 0.f) ? 1.f / sw : 0.f;
    *reinterpret_cast<float4*>(c + (size_t)b * Mn + m0) = o;
}

// rowsum[b,n] = sum_m (s+eps)*c[b,m]; r = (n<nrows && sum>0) ? 1/sum : 0.
// c already carries the column mask (zeros for invalid cols).
// WRITE_OUT (last iteration): reuse the loaded row to write
// out = (s+eps)*c*r  (zeros propagate the mask; guards keep r,c finite).
template <bool WRITE_OUT>
__global__ __launch_bounds__(256) void row_pass_kernel(
        const float* __restrict__ s, const float* __restrict__ c,
        const int* __restrict__ nrows, float* __restrict__ r,
        float* __restrict__ out) {
    const int b = blockIdx.x;
    const int n0 = blockIdx.y * RPB;
    const int t = threadIdx.x;
    const int m0 = t << 2;
    const int lane = t & 63;
    const int wv = t >> 6;
    float4 c4 = *reinterpret_cast<const float4*>(c + (size_t)b * Mn + m0);
    const int nr = nrows[b];
    __shared__ float red[4];
    __shared__ float rbc;
    for (int i = 0; i < RPB; ++i) {
        const int n = n0 + i;
        const size_t rowoff = ((size_t)b * Nn + n) * Mn + m0;
        float4 a = *reinterpret_cast<const float4*>(s + rowoff);
        float part = (a.x + EPS) * c4.x + (a.y + EPS) * c4.y
                   + (a.z + EPS) * c4.z + (a.w + EPS) * c4.w;
        #pragma unroll
        for (int off = 32; off > 0; off >>= 1)
            part += __shfl_down(part, off, 64);
        if (lane == 0) red[wv] = part;
        __syncthreads();
        if (t == 0) {
            float rs = red[0] + red[1] + red[2] + red[3];
            float rv = (n < nr && rs > 0.f) ? 1.f / rs : 0.f;
            if (WRITE_OUT) rbc = rv;
            else r[(size_t)b * Nn + n] = rv;
        }
        __syncthreads();
        if (WRITE_OUT) {
            float rv = rbc;
            float4 o;
            o.x = (a.x + EPS) * c4.x * rv;
            o.y = (a.y + EPS) * c4.y * rv;
            o.z = (a.z + EPS) * c4.z * rv;
            o.w = (a.w + EPS) * c4.w * rv;
            *reinterpret_cast<float4*>(out + rowoff) = o;
        }
        __syncthreads();  // protect red/rbc reuse across row iterations
    }
}

extern "C" void kernel_launch(void* const* d_in, const int* in_sizes, int n_in,
                              void* d_out, int out_size, void* d_ws, size_t ws_size,
                              hipStream_t stream) {
    const float* s     = (const float*)d_in[0];
    const int*   nrows = (const int*)d_in[1];
    const int*   ncols = (const int*)d_in[2];
    float* out = (float*)d_out;

    // workspace layout: r [B*N], c [B*M], partials [B*NSPLIT*M]  (~2.5 MB)
    float* r = (float*)d_ws;
    float* c = r + Bn * Nn;
    float* p = c + Bn * Mn;

    init_r_kernel<<<Bn * Nn / 256, 256, 0, stream>>>(r);
    for (int it = 0; it < 5; ++it) {
        col_partial_kernel<<<dim3(Bn, NSPLIT), 256, 0, stream>>>(s, r, p);
        col_final_kernel<<<Bn, 256, 0, stream>>>(p, ncols, c);
        if (it < 4)
            row_pass_kernel<false><<<dim3(Bn, Nn / RPB), 256, 0, stream>>>(
                s, c, nrows, r, nullptr);
        else
            row_pass_kernel<true><<<dim3(Bn, Nn / RPB), 256, 0, stream>>>(
                s, c, nrows, r, out);
    }
}

// Round 2
// 738.464 us; speedup vs baseline: 1.1487x; 1.1487x over previous
//
#include <hip/hip_runtime.h>

#define EPS 1e-4f

constexpr int Bn = 64;
constexpr int Nn = 1024;
constexpr int Mn = 1024;
constexpr int NSPLIT = 16;          // col-pass row chunks -> CHUNK=64 rows
constexpr int CHUNK  = Nn / NSPLIT; // 64
constexpr int SLOTS  = 2 * NSPLIT;  // 32 partial slots per sample (2 halves/block)

// ---- bf16 helpers (values are positive finite; no NaN concerns) ----
__device__ __forceinline__ unsigned pk2(float a, float b) {
    unsigned ua = __float_as_uint(a); ua = (ua + 0x7fffu + ((ua >> 16) & 1u)) >> 16;
    unsigned ub = __float_as_uint(b); ub = (ub + 0x7fffu + ((ub >> 16) & 1u)) >> 16;
    return ua | (ub << 16);
}
__device__ __forceinline__ float lo16(unsigned v) { return __uint_as_float(v << 16); }
__device__ __forceinline__ float hi16(unsigned v) { return __uint_as_float(v & 0xffff0000u); }

// ---- pass 0 fused: compress s+eps -> bf16 sc AND accumulate unmasked col sums.
// Block 256: threads 0..127 take row n (cols 8t..8t+7), threads 128..255 row n+1.
// f32 loads 2x float4 (32B/lane), bf16 store 1x uint4 (16B/lane) — all coalesced.
__global__ __launch_bounds__(256) void fuse0_kernel(
        const float* __restrict__ s, unsigned short* __restrict__ sc,
        float* __restrict__ p) {
    const int b = blockIdx.x, sp = blockIdx.y;
    const int t = threadIdx.x, half = t >> 7, tc = t & 127;
    float acc[8];
    #pragma unroll
    for (int k = 0; k < 8; ++k) acc[k] = 0.f;
    for (int j = 0; j < CHUNK; j += 2) {
        const int n = sp * CHUNK + j + half;
        const size_t roff = ((size_t)b * Nn + n) * Mn;
        const float4* src = reinterpret_cast<const float4*>(s + roff) + 2 * tc;
        float4 v0 = src[0], v1 = src[1];
        v0.x += EPS; v0.y += EPS; v0.z += EPS; v0.w += EPS;
        v1.x += EPS; v1.y += EPS; v1.z += EPS; v1.w += EPS;
        acc[0] += v0.x; acc[1] += v0.y; acc[2] += v0.z; acc[3] += v0.w;
        acc[4] += v1.x; acc[5] += v1.y; acc[6] += v1.z; acc[7] += v1.w;
        uint4 w = { pk2(v0.x, v0.y), pk2(v0.z, v0.w),
                    pk2(v1.x, v1.y), pk2(v1.z, v1.w) };
        reinterpret_cast<uint4*>(sc + roff)[tc] = w;
    }
    float* pp = p + ((size_t)(b * SLOTS + sp * 2 + half)) * Mn + tc * 8;
    float4 o0 = {acc[0], acc[1], acc[2], acc[3]};
    float4 o1 = {acc[4], acc[5], acc[6], acc[7]};
    *reinterpret_cast<float4*>(pp)     = o0;
    *reinterpret_cast<float4*>(pp + 4) = o1;
}

// ---- interior col pass over bf16 sc: p[b][slot][m] = sum_n sc[n,m]*r[n]
__global__ __launch_bounds__(256) void colred_kernel(
        const unsigned short* __restrict__ sc, const float* __restrict__ r,
        float* __restrict__ p) {
    const int b = blockIdx.x, sp = blockIdx.y;
    const int t = threadIdx.x, half = t >> 7, tc = t & 127;
    const float* rb = r + (size_t)b * Nn;
    float acc[8];
    #pragma unroll
    for (int k = 0; k < 8; ++k) acc[k] = 0.f;
    #pragma unroll 4
    for (int j = 0; j < CHUNK; j += 2) {
        const int n = sp * CHUNK + j + half;
        uint4 a = reinterpret_cast<const uint4*>(sc + ((size_t)b * Nn + n) * Mn)[tc];
        const float rn = rb[n];
        acc[0] += lo16(a.x) * rn; acc[1] += hi16(a.x) * rn;
        acc[2] += lo16(a.y) * rn; acc[3] += hi16(a.y) * rn;
        acc[4] += lo16(a.z) * rn; acc[5] += hi16(a.z) * rn;
        acc[6] += lo16(a.w) * rn; acc[7] += hi16(a.w) * rn;
    }
    float* pp = p + ((size_t)(b * SLOTS + sp * 2 + half)) * Mn + tc * 8;
    float4 o0 = {acc[0], acc[1], acc[2], acc[3]};
    float4 o1 = {acc[4], acc[5], acc[6], acc[7]};
    *reinterpret_cast<float4*>(pp)     = o0;
    *reinterpret_cast<float4*>(pp + 4) = o1;
}

// ---- reduce 32 partial slots -> masked, guarded reciprocal c[b][m]
__global__ __launch_bounds__(256) void col_final_kernel(
        const float* __restrict__ p, const int* __restrict__ ncols,
        float* __restrict__ c) {
    const int b = blockIdx.x;
    const int m0 = threadIdx.x << 2;
    float sx = 0.f, sy = 0.f, sz = 0.f, sw = 0.f;
    #pragma unroll
    for (int k = 0; k < SLOTS; ++k) {
        float4 v = *reinterpret_cast<const float4*>(
            p + ((size_t)(b * SLOTS + k)) * Mn + m0);
        sx += v.x; sy += v.y; sz += v.z; sw += v.w;
    }
    const int nc = ncols[b];
    float4 o;
    o.x = (m0 + 0 < nc && sx > 0.f) ? 1.f / sx : 0.f;
    o.y = (m0 + 1 < nc && sy > 0.f) ? 1.f / sy : 0.f;
    o.z = (m0 + 2 < nc && sz > 0.f) ? 1.f / sz : 0.f;
    o.w = (m0 + 3 < nc && sw > 0.f) ? 1.f / sw : 0.f;
    *reinterpret_cast<float4*>(c + (size_t)b * Mn + m0) = o;
}

// ---- interior row pass over bf16 sc: one WAVE per row, butterfly reduce,
// zero barriers. Block = 4 waves, 8 rows/wave -> grid (B, 32).
// Lane l covers cols [8l,8l+8) and [512+8l,512+8l+8); c preloaded per lane.
__global__ __launch_bounds__(256) void rowred_kernel(
        const unsigned short* __restrict__ sc, const float* __restrict__ c,
        const int* __restrict__ nrows, float* __restrict__ r) {
    const int b = blockIdx.x;
    const int t = threadIdx.x, w = t >> 6, l = t & 63;
    const int n0 = blockIdx.y * 32 + w * 8;
    const float4* cb = reinterpret_cast<const float4*>(c + (size_t)b * Mn);
    const float4 c0 = cb[2 * l], c1 = cb[2 * l + 1];
    const float4 c2 = cb[128 + 2 * l], c3 = cb[128 + 2 * l + 1];
    const int nr = nrows[b];
    for (int j = 0; j < 8; ++j) {
        const int n = n0 + j;
        const uint4* row = reinterpret_cast<const uint4*>(sc + ((size_t)b * Nn + n) * Mn);
        uint4 a = row[l], d = row[64 + l];
        float part =
            lo16(a.x) * c0.x + hi16(a.x) * c0.y + lo16(a.y) * c0.z + hi16(a.y) * c0.w +
            lo16(a.z) * c1.x + hi16(a.z) * c1.y + lo16(a.w) * c1.z + hi16(a.w) * c1.w +
            lo16(d.x) * c2.x + hi16(d.x) * c2.y + lo16(d.y) * c2.z + hi16(d.y) * c2.w +
            lo16(d.z) * c3.x + hi16(d.z) * c3.y + lo16(d.w) * c3.z + hi16(d.w) * c3.w;
        #pragma unroll
        for (int off = 1; off < 64; off <<= 1) part += __shfl_xor(part, off, 64);
        if (l == 0) r[(size_t)b * Nn + n] = (n < nr && part > 0.f) ? 1.f / part : 0.f;
    }
}

// ---- final pass: f32 s, compute last row factor in-wave and write output.
// One wave per row: 4x float4 loads held in registers, butterfly sum (all
// lanes get total), scale, 4x float4 stores. Zero barriers.
__global__ __launch_bounds__(256) void final_kernel(
        const float* __restrict__ s, const float* __restrict__ c,
        const int* __restrict__ nrows, float* __restrict__ out) {
    const int b = blockIdx.x;
    const int t = threadIdx.x, w = t >> 6, l = t & 63;
    const int n0 = blockIdx.y * 32 + w * 8;
    const float4* cb = reinterpret_cast<const float4*>(c + (size_t)b * Mn);
    float4 cc[4];
    #pragma unroll
    for (int k = 0; k < 4; ++k) cc[k] = cb[64 * k + l];
    const int nr = nrows[b];
    for (int j = 0; j < 8; ++j) {
        const int n = n0 + j;
        const size_t roff = ((size_t)b * Nn + n) * Mn;
        const float4* row = reinterpret_cast<const float4*>(s + roff);
        float4 a[4];
        float part = 0.f;
        #pragma unroll
        for (int k = 0; k < 4; ++k) {
            a[k] = row[64 * k + l];
            a[k].x += EPS; a[k].y += EPS; a[k].z += EPS; a[k].w += EPS;
            part += a[k].x * cc[k].x + a[k].y * cc[k].y
                  + a[k].z * cc[k].z + a[k].w * cc[k].w;
        }
        #pragma unroll
        for (int off = 1; off < 64; off <<= 1) part += __shfl_xor(part, off, 64);
        const float rv = (n < nr && part > 0.f) ? 1.f / part : 0.f;
        float4* orow = reinterpret_cast<float4*>(out + roff);
        #pragma unroll
        for (int k = 0; k < 4; ++k) {
            float4 o;
            o.x = a[k].x * cc[k].x * rv;
            o.y = a[k].y * cc[k].y * rv;
            o.z = a[k].z * cc[k].z * rv;
            o.w = a[k].w * cc[k].w * rv;
            orow[64 * k + l] = o;
        }
    }
}

extern "C" void kernel_launch(void* const* d_in, const int* in_sizes, int n_in,
                              void* d_out, int out_size, void* d_ws, size_t ws_size,
                              hipStream_t stream) {
    const float* s     = (const float*)d_in[0];
    const int*   nrows = (const int*)d_in[1];
    const int*   ncols = (const int*)d_in[2];
    float* out = (float*)d_out;

    // workspace: sc bf16 [B*N*M] (128 MiB) | p [B*SLOTS*M] (8 MB) | c | r
    unsigned short* sc = (unsigned short*)d_ws;
    float* p = (float*)(sc + (size_t)Bn * Nn * Mn);
    float* c = p + (size_t)Bn * SLOTS * Mn;
    float* r = c + (size_t)Bn * Mn;

    // i=0 col pass fused with bf16 compression (unmasked, r==1)
    fuse0_kernel<<<dim3(Bn, NSPLIT), 256, 0, stream>>>(s, sc, p);
    col_final_kernel<<<Bn, 256, 0, stream>>>(p, ncols, c);
    // i=1..8: alternate row/col reduce passes on compressed sc
    for (int it = 0; it < 4; ++it) {
        rowred_kernel<<<dim3(Bn, Nn / 32), 256, 0, stream>>>(sc, c, nrows, r);
        colred_kernel<<<dim3(Bn, NSPLIT), 256, 0, stream>>>(sc, r, p);
        col_final_kernel<<<Bn, 256, 0, stream>>>(p, ncols, c);
    }
    // i=9: final row normalization fused with output write (f32 precision)
    final_kernel<<<dim3(Bn, Nn / 32), 256, 0, stream>>>(s, c, nrows, out);
}

// Round 3
// 716.363 us; speedup vs baseline: 1.1841x; 1.0309x over previous
//
#include <hip/hip_runtime.h>

#define EPS 1e-4f

constexpr int Bn = 64;
constexpr int Nn = 1024;
constexpr int Mn = 1024;
constexpr int NSPLIT = 16;          // fuse0 row chunks -> CHUNK=64 rows
constexpr int CHUNK  = Nn / NSPLIT; // 64
constexpr int SLOT0  = 2 * NSPLIT;  // 32 partial slots/sample (fuse0)
constexpr int SLOT1  = 64;          // partial slots/sample (fused row+col pass)

// ---- bf16 helpers (values positive finite; round-to-nearest-even) ----
__device__ __forceinline__ unsigned pk2(float a, float b) {
    unsigned ua = __float_as_uint(a); ua = (ua + 0x7fffu + ((ua >> 16) & 1u)) >> 16;
    unsigned ub = __float_as_uint(b); ub = (ub + 0x7fffu + ((ub >> 16) & 1u)) >> 16;
    return ua | (ub << 16);
}
__device__ __forceinline__ float lo16(unsigned v) { return __uint_as_float(v << 16); }
__device__ __forceinline__ float hi16(unsigned v) { return __uint_as_float(v & 0xffff0000u); }

// ---- pass 0 fused: compress s+eps -> bf16 sc AND accumulate unmasked col sums.
// Block 256: threads 0..127 take row n (cols 8t..8t+7), threads 128..255 row n+1.
__global__ __launch_bounds__(256) void fuse0_kernel(
        const float* __restrict__ s, unsigned short* __restrict__ sc,
        float* __restrict__ p) {
    const int b = blockIdx.x, sp = blockIdx.y;
    const int t = threadIdx.x, half = t >> 7, tc = t & 127;
    float acc[8];
    #pragma unroll
    for (int k = 0; k < 8; ++k) acc[k] = 0.f;
    for (int j = 0; j < CHUNK; j += 2) {
        const int n = sp * CHUNK + j + half;
        const size_t roff = ((size_t)b * Nn + n) * Mn;
        const float4* src = reinterpret_cast<const float4*>(s + roff) + 2 * tc;
        float4 v0 = src[0], v1 = src[1];
        v0.x += EPS; v0.y += EPS; v0.z += EPS; v0.w += EPS;
        v1.x += EPS; v1.y += EPS; v1.z += EPS; v1.w += EPS;
        acc[0] += v0.x; acc[1] += v0.y; acc[2] += v0.z; acc[3] += v0.w;
        acc[4] += v1.x; acc[5] += v1.y; acc[6] += v1.z; acc[7] += v1.w;
        uint4 w = { pk2(v0.x, v0.y), pk2(v0.z, v0.w),
                    pk2(v1.x, v1.y), pk2(v1.z, v1.w) };
        reinterpret_cast<uint4*>(sc + roff)[tc] = w;
    }
    float* pp = p + ((size_t)(b * SLOT1 + sp * 2 + half)) * Mn + tc * 8;
    float4 o0 = {acc[0], acc[1], acc[2], acc[3]};
    float4 o1 = {acc[4], acc[5], acc[6], acc[7]};
    *reinterpret_cast<float4*>(pp)     = o0;
    *reinterpret_cast<float4*>(pp + 4) = o1;
}

// ---- reduce `slots` partial slots -> masked, guarded reciprocal c[b][m]
__global__ __launch_bounds__(256) void col_final_kernel(
        const float* __restrict__ p, const int* __restrict__ ncols,
        float* __restrict__ c, int slots) {
    const int b = blockIdx.x;
    const int m0 = threadIdx.x << 2;
    float sx = 0.f, sy = 0.f, sz = 0.f, sw = 0.f;
    for (int k = 0; k < slots; ++k) {
        float4 v = *reinterpret_cast<const float4*>(
            p + ((size_t)(b * SLOT1 + k)) * Mn + m0);
        sx += v.x; sy += v.y; sz += v.z; sw += v.w;
    }
    const int nc = ncols[b];
    float4 o;
    o.x = (m0 + 0 < nc && sx > 0.f) ? 1.f / sx : 0.f;
    o.y = (m0 + 1 < nc && sy > 0.f) ? 1.f / sy : 0.f;
    o.z = (m0 + 2 < nc && sz > 0.f) ? 1.f / sz : 0.f;
    o.w = (m0 + 3 < nc && sw > 0.f) ? 1.f / sw : 0.f;
    *reinterpret_cast<float4*>(c + (size_t)b * Mn + m0) = o;
}

// ---- FUSED row-pass + col-pass over bf16 sc, one sweep:
// one WAVE per row (16 rows/wave, grid (B,16), 4 waves/block):
//   rowsum = sum_m sc[n,m]*c[m]  (butterfly, all lanes get it)
//   rv     = (n<nrows && rowsum>0) ? 1/rowsum : 0     [never hits memory]
//   colacc[m] += sc[n,m]*rv
// After 16 rows, wave writes its 1024-col partial to slot y*4+w.
// Lane l owns cols {8l..8l+7, 512+8l..512+8l+7}.
__global__ __launch_bounds__(256) void rowcol_kernel(
        const unsigned short* __restrict__ sc, const float* __restrict__ c,
        const int* __restrict__ nrows, float* __restrict__ p) {
    const int b = blockIdx.x;
    const int t = threadIdx.x, w = t >> 6, l = t & 63;
    const int n0 = blockIdx.y * 64 + w * 16;
    const float4* cb = reinterpret_cast<const float4*>(c + (size_t)b * Mn);
    const float4 c0 = cb[2 * l], c1 = cb[2 * l + 1];
    const float4 c2 = cb[128 + 2 * l], c3 = cb[128 + 2 * l + 1];
    const int nr = nrows[b];
    float acc[16];
    #pragma unroll
    for (int k = 0; k < 16; ++k) acc[k] = 0.f;
    for (int j = 0; j < 16; ++j) {
        const int n = n0 + j;
        const uint4* row = reinterpret_cast<const uint4*>(sc + ((size_t)b * Nn + n) * Mn);
        uint4 a = row[l], d = row[64 + l];
        const float v0 = lo16(a.x), v1 = hi16(a.x), v2 = lo16(a.y), v3 = hi16(a.y);
        const float v4 = lo16(a.z), v5 = hi16(a.z), v6 = lo16(a.w), v7 = hi16(a.w);
        const float v8 = lo16(d.x), v9 = hi16(d.x), v10 = lo16(d.y), v11 = hi16(d.y);
        const float v12 = lo16(d.z), v13 = hi16(d.z), v14 = lo16(d.w), v15 = hi16(d.w);
        float part = v0 * c0.x + v1 * c0.y + v2 * c0.z + v3 * c0.w
                   + v4 * c1.x + v5 * c1.y + v6 * c1.z + v7 * c1.w
                   + v8 * c2.x + v9 * c2.y + v10 * c2.z + v11 * c2.w
                   + v12 * c3.x + v13 * c3.y + v14 * c3.z + v15 * c3.w;
        #pragma unroll
        for (int off = 1; off < 64; off <<= 1) part += __shfl_xor(part, off, 64);
        const float rv = (n < nr && part > 0.f) ? 1.f / part : 0.f;
        acc[0]  += v0 * rv;  acc[1]  += v1 * rv;  acc[2]  += v2 * rv;  acc[3]  += v3 * rv;
        acc[4]  += v4 * rv;  acc[5]  += v5 * rv;  acc[6]  += v6 * rv;  acc[7]  += v7 * rv;
        acc[8]  += v8 * rv;  acc[9]  += v9 * rv;  acc[10] += v10 * rv; acc[11] += v11 * rv;
        acc[12] += v12 * rv; acc[13] += v13 * rv; acc[14] += v14 * rv; acc[15] += v15 * rv;
    }
    float* pp = p + ((size_t)(b * SLOT1) + blockIdx.y * 4 + w) * Mn;
    float4 o;
    o = {acc[0], acc[1], acc[2], acc[3]};     *reinterpret_cast<float4*>(pp + 8 * l)           = o;
    o = {acc[4], acc[5], acc[6], acc[7]};     *reinterpret_cast<float4*>(pp + 8 * l + 4)       = o;
    o = {acc[8], acc[9], acc[10], acc[11]};   *reinterpret_cast<float4*>(pp + 512 + 8 * l)     = o;
    o = {acc[12], acc[13], acc[14], acc[15]}; *reinterpret_cast<float4*>(pp + 512 + 8 * l + 4) = o;
}

// ---- final pass: f32 s, compute last row factor in-wave and write output.
__global__ __launch_bounds__(256) void final_kernel(
        const float* __restrict__ s, const float* __restrict__ c,
        const int* __restrict__ nrows, float* __restrict__ out) {
    const int b = blockIdx.x;
    const int t = threadIdx.x, w = t >> 6, l = t & 63;
    const int n0 = blockIdx.y * 32 + w * 8;
    const float4* cb = reinterpret_cast<const float4*>(c + (size_t)b * Mn);
    float4 cc[4];
    #pragma unroll
    for (int k = 0; k < 4; ++k) cc[k] = cb[64 * k + l];
    const int nr = nrows[b];
    for (int j = 0; j < 8; ++j) {
        const int n = n0 + j;
        const size_t roff = ((size_t)b * Nn + n) * Mn;
        const float4* row = reinterpret_cast<const float4*>(s + roff);
        float4 a[4];
        float part = 0.f;
        #pragma unroll
        for (int k = 0; k < 4; ++k) {
            a[k] = row[64 * k + l];
            a[k].x += EPS; a[k].y += EPS; a[k].z += EPS; a[k].w += EPS;
            part += a[k].x * cc[k].x + a[k].y * cc[k].y
                  + a[k].z * cc[k].z + a[k].w * cc[k].w;
        }
        #pragma unroll
        for (int off = 1; off < 64; off <<= 1) part += __shfl_xor(part, off, 64);
        const float rv = (n < nr && part > 0.f) ? 1.f / part : 0.f;
        float4* orow = reinterpret_cast<float4*>(out + roff);
        #pragma unroll
        for (int k = 0; k < 4; ++k) {
            float4 o;
            o.x = a[k].x * cc[k].x * rv;
            o.y = a[k].y * cc[k].y * rv;
            o.z = a[k].z * cc[k].z * rv;
            o.w = a[k].w * cc[k].w * rv;
            orow[64 * k + l] = o;
        }
    }
}

extern "C" void kernel_launch(void* const* d_in, const int* in_sizes, int n_in,
                              void* d_out, int out_size, void* d_ws, size_t ws_size,
                              hipStream_t stream) {
    const float* s     = (const float*)d_in[0];
    const int*   nrows = (const int*)d_in[1];
    const int*   ncols = (const int*)d_in[2];
    float* out = (float*)d_out;

    // workspace: sc bf16 [B*N*M] (128 MiB) | p [B*SLOT1*M] (16 MB) | c (256 KB)
    unsigned short* sc = (unsigned short*)d_ws;
    float* p = (float*)(sc + (size_t)Bn * Nn * Mn);
    float* c = p + (size_t)Bn * SLOT1 * Mn;

    // i=0: col pass fused with bf16 compression (unmasked, r==1)
    fuse0_kernel<<<dim3(Bn, NSPLIT), 256, 0, stream>>>(s, sc, p);
    col_final_kernel<<<Bn, 256, 0, stream>>>(p, ncols, c, SLOT0);
    // i=1..8: four fused (row-norm + col-norm) sweeps over compressed sc
    for (int it = 0; it < 4; ++it) {
        rowcol_kernel<<<dim3(Bn, Nn / 64), 256, 0, stream>>>(sc, c, nrows, p);
        col_final_kernel<<<Bn, 256, 0, stream>>>(p, ncols, c, SLOT1);
    }
    // i=9: final row normalization fused with output write (f32 precision)
    final_kernel<<<dim3(Bn, Nn / 32), 256, 0, stream>>>(s, c, nrows, out);
}